// Round 1
// baseline (549.961 us; speedup 1.0000x reference)
//
#include <hip/hip_runtime.h>
#include <hip/hip_bf16.h>
#include <stdint.h>

typedef float f32x4 __attribute__((ext_vector_type(4)));
typedef float fvec4 __attribute__((ext_vector_type(4)));
typedef short bf16x8 __attribute__((ext_vector_type(8)));

#define HALF_K 24576
#define NUMELK 49152
#define BATCH  8192
#define BM 128
#define BK 64

__device__ __forceinline__ short f2bf(float f) {
  __hip_bfloat16 h = __float2bfloat16(f);
  return __builtin_bit_cast(short, h);
}

// ---------------- prep: Bws[256][49152] bf16 ----------------
// n<128 : Bws[n][k] = w_aff_W[n][k]           (combined-K order == w_feat order)
// n>=128: Bws[n][k] = b_aff_W[n-128][k<24576 ? k+24576 : k-24576]  (halves swapped)
__global__ __launch_bounds__(256)
void nnue_prep(const float* __restrict__ wW, const float* __restrict__ bW,
               short* __restrict__ Bws) {
  int k = (blockIdx.x * 256 + threadIdx.x) * 4;   // grid.x = 12288/256 = 48
  int n = blockIdx.y;                              // 0..255
  const float* src;
  if (n < 128) {
    src = wW + (size_t)n * NUMELK + k;
  } else {
    int kk = (k < HALF_K) ? (k + HALF_K) : (k - HALF_K);
    src = bW + (size_t)(n - 128) * NUMELK + kk;
  }
  fvec4 v = *(const fvec4*)src;
  unsigned a0 = (unsigned)(unsigned short)f2bf(v[0]) | ((unsigned)(unsigned short)f2bf(v[1]) << 16);
  unsigned a1 = (unsigned)(unsigned short)f2bf(v[2]) | ((unsigned)(unsigned short)f2bf(v[3]) << 16);
  uint2 o; o.x = a0; o.y = a1;
  *(uint2*)(Bws + (size_t)n * NUMELK + k) = o;
}

// ---------------- main GEMM: [8192 x 49152] x [49152 x 256] ----------------
// grid = (64, S). block (mt, ks) computes rows mt*128..+127 over K-chunk ks,
// writes exclusive fp32 partial[ks][m][n] (no atomics, deterministic).
__global__ __launch_bounds__(512)
void nnue_gemm(const float* __restrict__ white, const float* __restrict__ black,
               const short* __restrict__ Bws, float* __restrict__ partial,
               int kchunk) {
  __shared__ short Alds[BM * BK];   // [row][k], 16B chunks XOR-swizzled by (row&7)
  __shared__ short Blds[256 * BK];  // [col][k], 16B chunks XOR-swizzled by (col&7)

  const int t    = threadIdx.x;
  const int lane = t & 63;
  const int wid  = t >> 6;
  const int m0   = blockIdx.x * BM;
  const int ks   = blockIdx.y;
  const int k0   = ks * kchunk;

  f32x4 acc[4][4];
  const f32x4 zero = {0.f, 0.f, 0.f, 0.f};
#pragma unroll
  for (int i = 0; i < 4; ++i)
#pragma unroll
    for (int j = 0; j < 4; ++j) acc[i][j] = zero;

  const int arow = t >> 2;   // 0..127
  const int aq   = t & 3;    // 16 floats each
  const int wm = wid >> 2, wn = wid & 3;
  const int l15 = lane & 15, l4 = lane >> 4;

  const int niter = kchunk / BK;
  for (int kt = 0; kt < niter; ++kt) {
    const int kg = k0 + kt * BK;
    const float* A; int ka;
    if (kg < HALF_K) { A = white; ka = kg; } else { A = black; ka = kg - HALF_K; }

    // ---- stage A: 16 fp32 -> 16 bf16 -> 2x ds_write_b128 (swizzled)
    const float* asrc = A + (size_t)(m0 + arow) * HALF_K + ka + aq * 16;
    fvec4 v0 = ((const fvec4*)asrc)[0];
    fvec4 v1 = ((const fvec4*)asrc)[1];
    fvec4 v2 = ((const fvec4*)asrc)[2];
    fvec4 v3 = ((const fvec4*)asrc)[3];

    // ---- stage B: 4x 16B from Bws (linear src, swizzled LDS dest)
    uint4 bv[4];
    const short* bsrc = Bws + kg;
#pragma unroll
    for (int j = 0; j < 4; ++j) {
      int cid = t + j * 512;
      int col = cid >> 3, kc = cid & 7;
      bv[j] = *(const uint4*)(bsrc + (size_t)col * NUMELK + kc * 8);
    }

    bf16x8 alo, ahi;
    alo[0] = f2bf(v0[0]); alo[1] = f2bf(v0[1]); alo[2] = f2bf(v0[2]); alo[3] = f2bf(v0[3]);
    alo[4] = f2bf(v1[0]); alo[5] = f2bf(v1[1]); alo[6] = f2bf(v1[2]); alo[7] = f2bf(v1[3]);
    ahi[0] = f2bf(v2[0]); ahi[1] = f2bf(v2[1]); ahi[2] = f2bf(v2[2]); ahi[3] = f2bf(v2[3]);
    ahi[4] = f2bf(v3[0]); ahi[5] = f2bf(v3[1]); ahi[6] = f2bf(v3[2]); ahi[7] = f2bf(v3[3]);

    *(bf16x8*)&Alds[arow * BK + (((2 * aq)     ^ (arow & 7)) << 3)] = alo;
    *(bf16x8*)&Alds[arow * BK + (((2 * aq + 1) ^ (arow & 7)) << 3)] = ahi;
#pragma unroll
    for (int j = 0; j < 4; ++j) {
      int cid = t + j * 512;
      int col = cid >> 3, kc = cid & 7;
      *(uint4*)&Blds[col * BK + ((kc ^ (col & 7)) << 3)] = bv[j];
    }

    __syncthreads();

#pragma unroll
    for (int kstep = 0; kstep < 2; ++kstep) {
      bf16x8 af[4], bfr[4];
      const int kc = kstep * 4 + l4;
#pragma unroll
      for (int mf = 0; mf < 4; ++mf) {
        int row = wm * 64 + mf * 16 + l15;
        af[mf] = *(const bf16x8*)&Alds[row * BK + ((kc ^ (row & 7)) << 3)];
      }
#pragma unroll
      for (int nf = 0; nf < 4; ++nf) {
        int col = wn * 64 + nf * 16 + l15;
        bfr[nf] = *(const bf16x8*)&Blds[col * BK + ((kc ^ (col & 7)) << 3)];
      }
#pragma unroll
      for (int mf = 0; mf < 4; ++mf)
#pragma unroll
        for (int nf = 0; nf < 4; ++nf)
          acc[mf][nf] = __builtin_amdgcn_mfma_f32_16x16x32_bf16(af[mf], bfr[nf], acc[mf][nf], 0, 0, 0);
    }
    __syncthreads();
  }

  // ---- epilogue: C/D layout col=lane&15, row=(lane>>4)*4+r   [m89]
  float* P = partial + ((size_t)ks * BATCH + m0) * 256;
#pragma unroll
  for (int mf = 0; mf < 4; ++mf) {
    int row = wm * 64 + mf * 16 + l4 * 4;
#pragma unroll
    for (int nf = 0; nf < 4; ++nf) {
      int col = wn * 64 + nf * 16 + l15;
#pragma unroll
      for (int r = 0; r < 4; ++r)
        P[(size_t)(row + r) * 256 + col] = acc[mf][nf][r];
    }
  }
}

// ---------------- tail: partial-reduce + pov mix + relu + fc0..fc3 ----------------
__global__ __launch_bounds__(256)
void nnue_tail(const float* __restrict__ partial, int S,
               const float* __restrict__ pov,
               const float* __restrict__ waffb, const float* __restrict__ baffb,
               const float* __restrict__ fc0W, const float* __restrict__ fc0b,
               const float* __restrict__ fc1W, const float* __restrict__ fc1b,
               const float* __restrict__ fc2W, const float* __restrict__ fc2b,
               const float* __restrict__ fc3W, const float* __restrict__ fc3b,
               float* __restrict__ out) {
  __shared__ float w0s[32 * 256];   // stored at [(j<<8) | ((k+j)&255)]
  __shared__ float w1s[32 * 32];    // [(j<<5) | ((k+j)&31)]
  __shared__ float w2s[32 * 64];    // [(j<<6) | ((k+j)&63)]
  __shared__ float w3s[96];
  __shared__ float b0s[32], b1s[32], b2s[32];
  __shared__ float base_s[4][256];
  __shared__ float b3s;

  const int t = threadIdx.x;
  for (int i = t; i < 8192; i += 256) { int j = i >> 8, k = i & 255; w0s[(j << 8) | ((k + j) & 255)] = fc0W[i]; }
  for (int i = t; i < 1024; i += 256) { int j = i >> 5, k = i & 31;  w1s[(j << 5) | ((k + j) & 31)]  = fc1W[i]; }
  for (int i = t; i < 2048; i += 256) { int j = i >> 6, k = i & 63;  w2s[(j << 6) | ((k + j) & 63)]  = fc2W[i]; }
  if (t < 96) w3s[t] = fc3W[t];
  if (t < 32) { b0s[t] = fc0b[t]; b1s[t] = fc1b[t]; b2s[t] = fc2b[t]; }
  if (t == 0) b3s = fc3b[0];
  __syncthreads();

  const int wid = t >> 6, lane = t & 63;
  const int m = blockIdx.x * 4 + wid;
  const float pv = pov[m];

  // lane l holds concat[w_,b_] cols 4l..4l+3 (summed over K-splits, +bias)
  float val[4];
  {
    const float* p = partial + (size_t)m * 256 + lane * 4;
    fvec4 a = *(const fvec4*)p;
    for (int s = 1; s < S; ++s) a += *(const fvec4*)(p + (size_t)s * BATCH * 256);
    const int c0 = lane * 4;
#pragma unroll
    for (int j = 0; j < 4; ++j) {
      int c = c0 + j;
      float bias = (c < 128) ? waffb[c] : baffb[c - 128];
      val[j] = a[j] + bias;
    }
  }
#pragma unroll
  for (int j = 0; j < 4; ++j) {
    float other = __shfl(val[j], lane ^ 32, 64);   // partner holds the b_/w_ counterpart
    if (lane < 32) {
      int c = lane * 4 + j;
      float w = val[j], b = other;
      base_s[wid][c]       = fmaxf(pv * w + (1.f - pv) * b, 0.f);
      base_s[wid][c + 128] = fmaxf(pv * b + (1.f - pv) * w, 0.f);
    }
  }
  __syncthreads();

  const int j = lane & 31, half = lane >> 5;
  const float* bs = &base_s[wid][0];

  // fc0: each (j,half) pair sums 128 terms, then combines across halves
  float s0 = 0.f;
  for (int k = 0; k < 128; ++k) {
    int kk = half * 128 + k;
    s0 += bs[kk] * w0s[(j << 8) | ((kk + j) & 255)];
  }
  s0 += __shfl(s0, lane ^ 32, 64);
  float x0 = fmaxf(s0 + b0s[j], 0.f);

  // fc1 (32x32)
  float s1 = 0.f;
  for (int k = 0; k < 32; ++k)
    s1 += __shfl(x0, k, 64) * w1s[(j << 5) | ((k + j) & 31)];
  float x1 = fmaxf(s1 + b1s[j], 0.f);

  // fc2 (32x64), input = [x0, x1]
  float s2 = 0.f;
  for (int k = 0; k < 32; ++k) {
    s2 += __shfl(x0, k, 64) * w2s[(j << 6) | ((k + j) & 63)];
    s2 += __shfl(x1, k, 64) * w2s[(j << 6) | ((k + 32 + j) & 63)];
  }
  float x2 = fmaxf(s2 + b2s[j], 0.f);

  // fc3 (1x96), input = [x0, x1, x2]
  float s3 = 0.f;
  for (int k = 0; k < 32; ++k) {
    s3 += __shfl(x0, k, 64) * w3s[k];
    s3 += __shfl(x1, k, 64) * w3s[32 + k];
    s3 += __shfl(x2, k, 64) * w3s[64 + k];
  }
  if (lane == 0) out[m] = s3 + b3s;
}

extern "C" void kernel_launch(void* const* d_in, const int* in_sizes, int n_in,
                              void* d_out, int out_size, void* d_ws, size_t ws_size,
                              hipStream_t stream) {
  const float* pov   = (const float*)d_in[0];
  const float* white = (const float*)d_in[1];
  const float* black = (const float*)d_in[2];
  const float* wW    = (const float*)d_in[3];
  const float* wb    = (const float*)d_in[4];
  const float* bW    = (const float*)d_in[5];
  const float* bb    = (const float*)d_in[6];
  const float* fc0W  = (const float*)d_in[7];
  const float* fc0b  = (const float*)d_in[8];
  const float* fc1W  = (const float*)d_in[9];
  const float* fc1b  = (const float*)d_in[10];
  const float* fc2W  = (const float*)d_in[11];
  const float* fc2b  = (const float*)d_in[12];
  const float* fc3W  = (const float*)d_in[13];
  const float* fc3b  = (const float*)d_in[14];
  float* out = (float*)d_out;

  short* Bws = (short*)d_ws;
  const size_t BWS_BYTES = (size_t)256 * NUMELK * 2;      // 25,165,824
  float* partial = (float*)((char*)d_ws + BWS_BYTES);
  const size_t PART1 = (size_t)BATCH * 256 * 4;           // 8,388,608

  int S = 4;                                              // K-split factor
  if (ws_size < BWS_BYTES + 4 * PART1) S = 2;
  if (ws_size < BWS_BYTES + 2 * PART1) S = 1;

  nnue_prep<<<dim3(48, 256), 256, 0, stream>>>(wW, bW, Bws);
  nnue_gemm<<<dim3(BATCH / BM, S), 512, 0, stream>>>(white, black, Bws, partial, NUMELK / S);
  nnue_tail<<<dim3(BATCH / 4), 256, 0, stream>>>(partial, S, pov, wb, bb,
      fc0W, fc0b, fc1W, fc1b, fc2W, fc2b, fc3W, fc3b, out);
}